// Round 3
// baseline (351.973 us; speedup 1.0000x reference)
//
#include <hip/hip_runtime.h>
#include <hip/hip_bf16.h>
#include <math.h>

#define B_ 2
#define N_ 4096
#define C_ 256
#define H_ 8
#define K_ 32
#define NP_ (B_*N_)
#define CAPC 512

typedef __attribute__((ext_vector_type(8))) short bf16x8;
typedef __attribute__((ext_vector_type(4))) float f32x4;
typedef __attribute__((ext_vector_type(4))) unsigned short ushort4_t;

__device__ __forceinline__ float bf2f(unsigned short v){
    union { unsigned int u; float f; } x; x.u = ((unsigned int)v) << 16; return x.f;
}
__device__ __forceinline__ unsigned short f2bf(float f){
    union { float f; unsigned int u; } x; x.f = f;
    return (unsigned short)((x.u + 0x7FFFu + ((x.u >> 16) & 1u)) >> 16);
}

// ---------------- batched weight fp32 -> bf16 into contiguous Wbase ----------------
__global__ __launch_bounds__(256) void k_cvt_all(
    const float* __restrict__ s0, const float* __restrict__ s1,
    const float* __restrict__ s2, const float* __restrict__ s3,
    const float* __restrict__ s4, const float* __restrict__ s5,
    const float* __restrict__ s6, unsigned short* __restrict__ dst)
{
    int i = blockIdx.x*256 + threadIdx.x;   // 3328*256 = 851968 exactly
    float v;
    if (i < 327680){
        int seg = i >> 16, off = i & 65535;
        const float* s = (seg==0)?s0:(seg==1)?s1:(seg==2)?s2:(seg==3)?s3:s4;
        v = s[off];
    } else if (i < 720896){
        v = s5[i - 327680];
    } else {
        v = s6[i - 720896];
    }
    dst[i] = f2bf(v);
}

// ---------------- LN stats over C for featA (B,C,N) ----------------
__global__ __launch_bounds__(256) void k_ln_stats(const float* __restrict__ fa, float* __restrict__ stats){
    __shared__ float part[2][4][64];
    const int lane = threadIdx.x & 63, wq = threadIdx.x >> 6;
    const int pbase = blockIdx.x * 64;
    const int p = pbase + lane;
    const int b = p >> 12, n = p & 4095;
    const float* base = fa + (size_t)b*C_*N_ + n;
    float s = 0.f, sq = 0.f;
    #pragma unroll 8
    for (int i = 0; i < 64; i++){
        float x = base[(size_t)(wq*64 + i)*N_];
        s += x; sq = fmaf(x, x, sq);
    }
    part[0][wq][lane] = s; part[1][wq][lane] = sq;
    __syncthreads();
    if (threadIdx.x < 64){
        int l = threadIdx.x;
        float S = part[0][0][l]+part[0][1][l]+part[0][2][l]+part[0][3][l];
        float Q = part[1][0][l]+part[1][1][l]+part[1][2][l]+part[1][3][l];
        float m = S*(1.f/256.f);
        float var = Q*(1.f/256.f) - m*m;
        stats[2*(pbase+l)]   = m;
        stats[2*(pbase+l)+1] = rsqrtf(var + 1e-5f);
    }
}

// ---------------- transpose (B,C,N)->(B,N,C) bf16, optional LN ----------------
template<int DO_LN>
__global__ __launch_bounds__(256) void k_transpose(const float* __restrict__ src,
                            unsigned short* __restrict__ dst, int dstStride,
                            const float* __restrict__ stats,
                            const float* __restrict__ lnw, const float* __restrict__ lnb){
    __shared__ float tile[64][65];
    const int b = blockIdx.z;
    const int n0 = blockIdx.x*64, c0 = blockIdx.y*64;
    const int tx = threadIdx.x & 63, ty = threadIdx.x >> 6;
    const float* sp = src + (size_t)b*C_*N_;
    #pragma unroll
    for (int i = 0; i < 16; i++){
        int cr = ty + i*4;
        tile[cr][tx] = sp[(size_t)(c0+cr)*N_ + n0 + tx];
    }
    __syncthreads();
    const int c = c0 + tx;
    #pragma unroll
    for (int i = 0; i < 16; i++){
        int nr = ty + i*4;
        int n = n0 + nr;
        float x = tile[tx][nr];
        int p = (b<<12) + n;
        if (DO_LN){
            float mean = stats[2*p], rstd = stats[2*p+1];
            x = (x - mean)*rstd*lnw[c] + lnb[c];
        }
        dst[(size_t)p*dstStride + c] = f2bf(x);
    }
}

// ---------------- KNN: order-statistic threshold + exact rank among candidates ----
// 4 queries per block; candidate xyz points held in registers across queries.
__global__ __launch_bounds__(256) void k_knn(const float* __restrict__ xyzA,
        const float* __restrict__ xyzB, int* __restrict__ knn){
    const int tid = threadIdx.x, wv = tid >> 6;
    const int bq = blockIdx.x;              // 2048 blocks
    const int b  = bq >> 10;                // batch
    const float* pb = xyzB + (size_t)b*N_*3;
    float px[16], py[16], pz[16];
    #pragma unroll
    for (int i = 0; i < 16; i++){
        int m = tid + i*256;
        px[i] = pb[m*3]; py[i] = pb[m*3+1]; pz[i] = pb[m*3+2];
    }
    __shared__ unsigned long long cand[CAPC];
    __shared__ unsigned long long vsh[4];
    __shared__ unsigned int ctr;
    for (int q = 0; q < 4; q++){
        const int p = bq*4 + q;
        const float* pa = xyzA + (size_t)p*3;
        const float ax = pa[0], ay = pa[1], az = pa[2];
        const float sa = ax*ax + ay*ay + az*az;
        unsigned long long key[16];
        unsigned long long mn = ~0ull;
        #pragma unroll
        for (int i = 0; i < 16; i++){
            int m = tid + i*256;
            float d2 = (sa + px[i]*px[i] + py[i]*py[i] + pz[i]*pz[i])
                       - 2.f*(ax*px[i] + ay*py[i] + az*pz[i]);
            union { float f; unsigned int u; } cv; cv.f = d2;
            unsigned int u = cv.u ^ (0x80000000u | (unsigned int)((int)cv.u >> 31));
            key[i] = (((unsigned long long)u) << 12) | (unsigned int)m;
            mn = key[i] < mn ? key[i] : mn;
        }
        // in-wave rank of per-thread minima (64 unique values)
        unsigned int rk = 0;
        for (int j = 0; j < 64; j++){
            unsigned long long o = __shfl(mn, j, 64);
            rk += (o < mn) ? 1u : 0u;
        }
        if (tid == 0) ctr = 0u;
        if (rk == 31u) vsh[wv] = mn;       // wave's 32nd-smallest minimum
        __syncthreads();
        unsigned long long v0 = vsh[0] < vsh[1] ? vsh[0] : vsh[1];
        unsigned long long v1 = vsh[2] < vsh[3] ? vsh[2] : vsh[3];
        unsigned long long v  = v0 < v1 ? v0 : v1;   // guaranteed >= T_32
        #pragma unroll
        for (int i = 0; i < 16; i++){
            if (key[i] <= v){
                unsigned int s = atomicAdd(&ctr, 1u);
                if (s < CAPC) cand[s] = key[i];
            }
        }
        __syncthreads();
        const unsigned int C = ctr;
        if (C <= CAPC){
            for (unsigned int i = tid; i < C; i += 256){
                unsigned long long mk = cand[i];
                unsigned int rank = 0;
                for (unsigned int j = 0; j < C; j++) rank += (cand[j] < mk) ? 1u : 0u;
                if (rank < K_) knn[(size_t)p*K_ + rank] = (int)(mk & 0xFFFull);
            }
        } else {
            // never expected; exact fallback: 32 rounds of block-min extraction
            for (int it = 0; it < K_; it++){
                unsigned long long mm = ~0ull;
                #pragma unroll
                for (int i = 0; i < 16; i++) mm = key[i] < mm ? key[i] : mm;
                #pragma unroll
                for (int off = 1; off < 64; off <<= 1){
                    unsigned long long o = __shfl_xor(mm, off, 64);
                    mm = o < mm ? o : mm;
                }
                if ((tid & 63) == 0) vsh[wv] = mm;
                __syncthreads();
                unsigned long long a0 = vsh[0] < vsh[1] ? vsh[0] : vsh[1];
                unsigned long long a1 = vsh[2] < vsh[3] ? vsh[2] : vsh[3];
                unsigned long long bm = a0 < a1 ? a0 : a1;
                if (tid == 0) knn[(size_t)p*K_ + it] = (int)(bm & 0xFFFull);
                #pragma unroll
                for (int i = 0; i < 16; i++) if (key[i] == bm) key[i] = ~0ull;
                __syncthreads();
            }
        }
        __syncthreads();
    }
}

// ---------------- generic MFMA GEMM: Y = epilogue(X(M,Kin) * W(O,Kin)^T) ----------------
// MODE 0: bias by 256-col range (e0|e1|e2) -> bf16 Y
// MODE 1: *scale(bn)+shift, relu -> bf16 Y   (e0=scale base, e1=shift)
// MODE 2: +bias(e0) + residual featA, write fp32 out transposed (B,C,N)
template<int MODE>
__global__ __launch_bounds__(256) void k_gemm(
    const unsigned short* __restrict__ X, int ldx,
    const unsigned short* __restrict__ W, int Kin,
    const float* __restrict__ e0, const float* __restrict__ e1, const float* __restrict__ e2,
    unsigned short* __restrict__ Y, int ldy,
    const float* __restrict__ resid, float* __restrict__ out)
{
    const int wid = threadIdx.x >> 6, lane = threadIdx.x & 63;
    const int lr = lane & 15, lg = lane >> 4;
    const int mw = blockIdx.x * 128 + wid * 32;
    const int cn = blockIdx.y * 64;
    f32x4 acc[2][4] = {};
    const unsigned short* xr0 = X + (size_t)(mw + lr) * ldx;
    const unsigned short* xr1 = xr0 + (size_t)16 * ldx;
    const unsigned short* wr0 = W + (size_t)(cn + lr) * Kin;
    for (int k0 = 0; k0 < Kin; k0 += 32){
        const int k = k0 + lg*8;
        bf16x8 a0 = *(const bf16x8*)(xr0 + k);
        bf16x8 a1 = *(const bf16x8*)(xr1 + k);
        #pragma unroll
        for (int ni = 0; ni < 4; ni++){
            bf16x8 bf = *(const bf16x8*)(wr0 + (size_t)ni*16*Kin + k);
            acc[0][ni] = __builtin_amdgcn_mfma_f32_16x16x32_bf16(a0, bf, acc[0][ni], 0, 0, 0);
            acc[1][ni] = __builtin_amdgcn_mfma_f32_16x16x32_bf16(a1, bf, acc[1][ni], 0, 0, 0);
        }
    }
    #pragma unroll
    for (int mi = 0; mi < 2; mi++){
        const int pbase = mw + mi*16 + lg*4;
        #pragma unroll
        for (int ni = 0; ni < 4; ni++){
            const int o = cn + ni*16 + lr;
            if (MODE == 0){
                const float* bp = (o < 256) ? e0 : ((o < 512) ? e1 : e2);
                float bias = bp[o & 255];
                #pragma unroll
                for (int r = 0; r < 4; r++)
                    Y[(size_t)(pbase + r)*ldy + o] = f2bf(acc[mi][ni][r] + bias);
            } else if (MODE == 1){
                float sc = e0[o] * 0.9999950000374997f;   // rsqrt(1+1e-5)*bn_g
                float sh = e1[o];
                #pragma unroll
                for (int r = 0; r < 4; r++){
                    float vv = fmaf(acc[mi][ni][r], sc, sh);
                    Y[(size_t)(pbase + r)*ldy + o] = f2bf(fmaxf(vv, 0.f));
                }
            } else {
                float bias = e0[o];
                const int b = pbase >> 12, nn = pbase & 4095;
                const size_t adr = ((size_t)b*C_ + o)*N_ + nn;
                f32x4 rv = *(const f32x4*)(resid + adr);
                f32x4 ov;
                #pragma unroll
                for (int r = 0; r < 4; r++) ov[r] = acc[mi][ni][r] + bias + rv[r];
                *(f32x4*)(out + adr) = ov;
            }
        }
    }
}

// ---------------- dual-path neighbor attention, one wave per point ----------------
// QQ: (8192,512) cols 0-255=q_s, 256-511=q_d ; KVD: (8192,768) cols 0-255=k_s, 256-511=v, 512-767=k_d
__global__ __launch_bounds__(256) void k_attn(
    const unsigned short* __restrict__ QQ, const unsigned short* __restrict__ KVD,
    const int* __restrict__ KNN,
    const float* __restrict__ lnsw, const float* __restrict__ lnsb,
    const float* __restrict__ lndw, const float* __restrict__ lndb,
    unsigned short* __restrict__ F)
{
    __shared__ float qs_l[4][256], qd_l[4][256];
    __shared__ float ws_l[4][8][32], wd_l[4][8][32];
    __shared__ int idx_l[4][32];
    const int wid = threadIdx.x >> 6, lane = threadIdx.x & 63;
    const int p = blockIdx.x*4 + wid;
    const int b = p >> 12;
    {
        ushort4_t qv = *(const ushort4_t*)(QQ + (size_t)p*512 + lane*4);
        ushort4_t dv = *(const ushort4_t*)(QQ + (size_t)p*512 + 256 + lane*4);
        #pragma unroll
        for (int j = 0; j < 4; j++){
            qs_l[wid][lane*4+j] = bf2f(qv[j]);
            qd_l[wid][lane*4+j] = bf2f(dv[j]);
        }
        if (lane < 32) idx_l[wid][lane] = KNN[(size_t)p*K_ + lane];
    }
    __syncthreads();
    const int kk = lane & 31, hg = lane >> 5;
    {
        const int nbr = idx_l[wid][kk];
        const unsigned short* base = KVD + ((size_t)(b<<12) + nbr)*768;
        const unsigned short* krow = base;
        const unsigned short* drow = base + 512;
        #pragma unroll
        for (int j = 0; j < 4; j++){
            const int h = hg*4 + j;
            const float* qs_h = &qs_l[wid][h*32];
            const float* qd_h = &qd_l[wid][h*32];
            const bf16x8* kr = (const bf16x8*)(krow + h*32);
            const bf16x8* dr = (const bf16x8*)(drow + h*32);
            float s = 0.f, dd = 0.f;
            #pragma unroll
            for (int c8 = 0; c8 < 4; c8++){
                bf16x8 kv = kr[c8], dvv = dr[c8];
                #pragma unroll
                for (int e = 0; e < 8; e++){
                    int d = c8*8 + e;
                    s = fmaf(qs_h[d], bf2f((unsigned short)kv[e]), s);
                    float df = qd_h[d] - bf2f((unsigned short)dvv[e]);
                    dd = fmaf(df, df, dd);
                }
            }
            float sim = s * 0.17677669529663687f;   // 1/sqrt(32)
            float dist = sqrtf(dd);
            float m1 = sim, m2 = dist;
            #pragma unroll
            for (int off = 1; off < 32; off <<= 1){
                m1 = fmaxf(m1, __shfl_xor(m1, off, 64));
                m2 = fmaxf(m2, __shfl_xor(m2, off, 64));
            }
            float e1v = __expf(sim - m1);
            float e2v = __expf(dist - m2);
            float s1 = e1v, s2 = e2v;
            #pragma unroll
            for (int off = 1; off < 32; off <<= 1){
                s1 += __shfl_xor(s1, off, 64);
                s2 += __shfl_xor(s2, off, 64);
            }
            ws_l[wid][h][kk] = e1v / s1;
            wd_l[wid][h][kk] = e2v / s2;
        }
    }
    __syncthreads();
    const int d = kk;
    float cs[4] = {0,0,0,0}, cd[4] = {0,0,0,0};
    for (int t = 0; t < 32; t++){
        const int nbr = idx_l[wid][t];
        const unsigned short* vrow = KVD + ((size_t)(b<<12) + nbr)*768 + 256;
        #pragma unroll
        for (int j = 0; j < 4; j++){
            const int h = hg*4 + j;
            float vf = bf2f(vrow[h*32 + d]);
            cs[j] = fmaf(ws_l[wid][h][t], vf, cs[j]);
            cd[j] = fmaf(wd_l[wid][h][t], vf, cd[j]);
        }
    }
    float s1 = 0.f, q1 = 0.f, s2 = 0.f, q2 = 0.f;
    #pragma unroll
    for (int j = 0; j < 4; j++){
        s1 += cs[j]; q1 = fmaf(cs[j], cs[j], q1);
        s2 += cd[j]; q2 = fmaf(cd[j], cd[j], q2);
    }
    #pragma unroll
    for (int off = 1; off < 64; off <<= 1){
        s1 += __shfl_xor(s1, off, 64); q1 += __shfl_xor(q1, off, 64);
        s2 += __shfl_xor(s2, off, 64); q2 += __shfl_xor(q2, off, 64);
    }
    float m1 = s1*(1.f/256.f), m2 = s2*(1.f/256.f);
    float r1 = rsqrtf(q1*(1.f/256.f) - m1*m1 + 1e-5f);
    float r2 = rsqrtf(q2*(1.f/256.f) - m2*m2 + 1e-5f);
    unsigned short* frow = F + (size_t)p*768;
    #pragma unroll
    for (int j = 0; j < 4; j++){
        int c = (hg*4 + j)*32 + d;
        frow[256 + c] = f2bf((cs[j]-m1)*r1*lnsw[c] + lnsb[c]);
        frow[512 + c] = f2bf((cd[j]-m2)*r2*lndw[c] + lndb[c]);
    }
}

extern "C" void kernel_launch(void* const* d_in, const int* in_sizes, int n_in,
                              void* d_out, int out_size, void* d_ws, size_t ws_size,
                              hipStream_t stream)
{
    const float* xyzA   = (const float*)d_in[0];
    const float* xyzB   = (const float*)d_in[1];
    const float* featA  = (const float*)d_in[2];
    const float* featB  = (const float*)d_in[3];
    const float* ln_in_w= (const float*)d_in[4];
    const float* ln_in_b= (const float*)d_in[5];
    const float* wq  = (const float*)d_in[6];
    const float* bq  = (const float*)d_in[7];
    const float* wk  = (const float*)d_in[8];
    const float* bk  = (const float*)d_in[9];
    const float* wv  = (const float*)d_in[10];
    const float* bv  = (const float*)d_in[11];
    const float* wqd = (const float*)d_in[12];
    const float* bqd = (const float*)d_in[13];
    const float* wkd = (const float*)d_in[14];
    const float* bkd = (const float*)d_in[15];
    const float* lnsw = (const float*)d_in[16];
    const float* lnsb = (const float*)d_in[17];
    const float* lndw = (const float*)d_in[18];
    const float* lndb = (const float*)d_in[19];
    const float* fw1 = (const float*)d_in[20];
    const float* bng = (const float*)d_in[21];
    const float* bnb = (const float*)d_in[22];
    const float* fw2 = (const float*)d_in[23];
    const float* fb2 = (const float*)d_in[24];
    float* out = (float*)d_out;
    char* ws = (char*)d_ws;

    unsigned short* F    = (unsigned short*)(ws + 0);          // 8192*768 bf16
    unsigned short* XBT  = (unsigned short*)(ws + 12582912);   // 8192*256
    unsigned short* QQ   = (unsigned short*)(ws + 16777216);   // 8192*512
    unsigned short* KVD  = (unsigned short*)(ws + 25165824);   // 8192*768
    unsigned short* Y1   = (unsigned short*)(ws + 37748736);   // 8192*512
    int*            KNNi = (int*)(ws + 46137344);              // 8192*32
    float*          STATS= (float*)(ws + 47185920);            // 8192*2
    unsigned short* Wb   = (unsigned short*)(ws + 47251456);   // 851968 bf16
    unsigned short* WQcat = Wb;                // 512x256
    unsigned short* WKVD  = Wb + 131072;       // 768x256
    unsigned short* W1b   = Wb + 327680;       // 512x768
    unsigned short* W2b   = Wb + 720896;       // 256x512

    k_cvt_all<<<3328, 256, 0, stream>>>(wq, wqd, wk, wv, wkd, fw1, fw2, Wb);

    k_ln_stats<<<128, 256, 0, stream>>>(featA, STATS);
    k_transpose<1><<<dim3(64,4,2), 256, 0, stream>>>(featA, F, 768, STATS, ln_in_w, ln_in_b);
    k_transpose<0><<<dim3(64,4,2), 256, 0, stream>>>(featB, XBT, 256, nullptr, nullptr, nullptr);
    k_knn<<<2048, 256, 0, stream>>>(xyzA, xyzB, KNNi);

    k_gemm<0><<<dim3(64,8), 256, 0, stream>>>(F,   768, WQcat, 256, bq, bqd, nullptr, QQ, 512, nullptr, nullptr);
    k_gemm<0><<<dim3(64,12), 256, 0, stream>>>(XBT, 256, WKVD, 256, bk, bv, bkd, KVD, 768, nullptr, nullptr);

    k_attn<<<2048, 256, 0, stream>>>(QQ, KVD, KNNi, lnsw, lnsb, lndw, lndb, F);

    k_gemm<1><<<dim3(64,8), 256, 0, stream>>>(F,  768, W1b, 768, bng, bnb, nullptr, Y1, 512, nullptr, nullptr);
    k_gemm<2><<<dim3(64,4), 256, 0, stream>>>(Y1, 512, W2b, 512, fb2, nullptr, nullptr, nullptr, 0, featA, out);
}

// Round 4
// 253.853 us; speedup vs baseline: 1.3865x; 1.3865x over previous
//
#include <hip/hip_runtime.h>
#include <hip/hip_bf16.h>
#include <math.h>

#define B_ 2
#define N_ 4096
#define C_ 256
#define H_ 8
#define K_ 32
#define NP_ (B_*N_)
#define CAPW 256

typedef __attribute__((ext_vector_type(8))) short bf16x8;
typedef __attribute__((ext_vector_type(4))) float f32x4;
typedef __attribute__((ext_vector_type(4))) unsigned short ushort4_t;

__device__ __forceinline__ float bf2f(unsigned short v){
    union { unsigned int u; float f; } x; x.u = ((unsigned int)v) << 16; return x.f;
}
__device__ __forceinline__ unsigned short f2bf(float f){
    union { float f; unsigned int u; } x; x.f = f;
    return (unsigned short)((x.u + 0x7FFFu + ((x.u >> 16) & 1u)) >> 16);
}

// ---------------- batched weight fp32 -> bf16 into contiguous Wbase ----------------
__global__ __launch_bounds__(256) void k_cvt_all(
    const float* __restrict__ s0, const float* __restrict__ s1,
    const float* __restrict__ s2, const float* __restrict__ s3,
    const float* __restrict__ s4, const float* __restrict__ s5,
    const float* __restrict__ s6, unsigned short* __restrict__ dst)
{
    int i = blockIdx.x*256 + threadIdx.x;   // 3328*256 = 851968 exactly
    float v;
    if (i < 327680){
        int seg = i >> 16, off = i & 65535;
        const float* s = (seg==0)?s0:(seg==1)?s1:(seg==2)?s2:(seg==3)?s3:s4;
        v = s[off];
    } else if (i < 720896){
        v = s5[i - 327680];
    } else {
        v = s6[i - 720896];
    }
    dst[i] = f2bf(v);
}

// ---------------- LN stats over C for featA (B,C,N) ----------------
__global__ __launch_bounds__(256) void k_ln_stats(const float* __restrict__ fa, float* __restrict__ stats){
    __shared__ float part[2][4][64];
    const int lane = threadIdx.x & 63, wq = threadIdx.x >> 6;
    const int pbase = blockIdx.x * 64;
    const int p = pbase + lane;
    const int b = p >> 12, n = p & 4095;
    const float* base = fa + (size_t)b*C_*N_ + n;
    float s = 0.f, sq = 0.f;
    #pragma unroll 8
    for (int i = 0; i < 64; i++){
        float x = base[(size_t)(wq*64 + i)*N_];
        s += x; sq = fmaf(x, x, sq);
    }
    part[0][wq][lane] = s; part[1][wq][lane] = sq;
    __syncthreads();
    if (threadIdx.x < 64){
        int l = threadIdx.x;
        float S = part[0][0][l]+part[0][1][l]+part[0][2][l]+part[0][3][l];
        float Q = part[1][0][l]+part[1][1][l]+part[1][2][l]+part[1][3][l];
        float m = S*(1.f/256.f);
        float var = Q*(1.f/256.f) - m*m;
        stats[2*(pbase+l)]   = m;
        stats[2*(pbase+l)+1] = rsqrtf(var + 1e-5f);
    }
}

// ---------------- transpose (B,C,N)->(B,N,C) bf16, optional LN ----------------
template<int DO_LN>
__global__ __launch_bounds__(256) void k_transpose(const float* __restrict__ src,
                            unsigned short* __restrict__ dst, int dstStride,
                            const float* __restrict__ stats,
                            const float* __restrict__ lnw, const float* __restrict__ lnb){
    __shared__ float tile[64][65];
    const int b = blockIdx.z;
    const int n0 = blockIdx.x*64, c0 = blockIdx.y*64;
    const int tx = threadIdx.x & 63, ty = threadIdx.x >> 6;
    const float* sp = src + (size_t)b*C_*N_;
    #pragma unroll
    for (int i = 0; i < 16; i++){
        int cr = ty + i*4;
        tile[cr][tx] = sp[(size_t)(c0+cr)*N_ + n0 + tx];
    }
    __syncthreads();
    const int c = c0 + tx;
    #pragma unroll
    for (int i = 0; i < 16; i++){
        int nr = ty + i*4;
        int n = n0 + nr;
        float x = tile[tx][nr];
        int p = (b<<12) + n;
        if (DO_LN){
            float mean = stats[2*p], rstd = stats[2*p+1];
            x = (x - mean)*rstd*lnw[c] + lnb[c];
        }
        dst[(size_t)p*dstStride + c] = f2bf(x);
    }
}

// ---------------- KNN: one query per wave, zero cross-wave coordination ----------
// Per wave: 64 candidates/lane in registers (32-bit monotone d2; index = i*64+lane),
// threshold v = 32nd-smallest of the 64 lane-minima (>= true T32), compact keys<=v
// to per-wave LDS via shuffle-scan, exact rank among ~44 candidates, direct write.
__global__ __launch_bounds__(256) void k_knn(const float* __restrict__ xyzA,
        const float* __restrict__ xyzB, int* __restrict__ knn){
    const int wv = threadIdx.x >> 6, lane = threadIdx.x & 63;
    const int p = blockIdx.x*4 + wv;            // 2048 blocks x 4 waves
    const int b = p >> 12;
    const float* pb = xyzB + (size_t)b*N_*3;
    const float* pa = xyzA + (size_t)p*3;
    const float ax = pa[0], ay = pa[1], az = pa[2];
    const float sa = ax*ax + ay*ay + az*az;

    unsigned int k32[64];
    unsigned int bestk = 0xFFFFFFFFu; unsigned int besti = 0;
    #pragma unroll
    for (int i = 0; i < 64; i++){
        const int m = i*64 + lane;
        float bx = pb[m*3], by = pb[m*3+1], bz = pb[m*3+2];
        float d2 = (sa + bx*bx + by*by + bz*bz) - 2.f*(ax*bx + ay*by + az*bz);
        union { float f; unsigned int u; } cv; cv.f = d2;
        unsigned int u = cv.u ^ (0x80000000u | (unsigned int)((int)cv.u >> 31));
        k32[i] = u;
        if (u < bestk){ bestk = u; besti = (unsigned int)i; }
    }
    const unsigned long long mn =
        (((unsigned long long)bestk) << 12) | (unsigned long long)(besti*64u + (unsigned int)lane);

    // rank of this lane's minimum among the wave's 64 minima (keys unique)
    unsigned int rk = 0;
    for (int j = 0; j < 64; j++){
        unsigned long long o = __shfl(mn, j, 64);
        rk += (o < mn) ? 1u : 0u;
    }
    unsigned long long sel = (rk == 31u) ? mn : ~0ull;
    #pragma unroll
    for (int off = 32; off; off >>= 1){
        unsigned long long o = __shfl_xor(sel, off, 64);
        sel = o < sel ? o : sel;
    }
    const unsigned long long v = sel;                 // guaranteed >= T32
    const unsigned int vhi = (unsigned int)(v >> 12);
    const unsigned int vlo = (unsigned int)(v & 0xFFFull);

    // count qualifying keys, exclusive shuffle-scan for compaction offsets
    unsigned int cnt = 0;
    #pragma unroll
    for (int i = 0; i < 64; i++){
        const unsigned int m = (unsigned int)(i*64 + lane);
        cnt += (k32[i] < vhi || (k32[i] == vhi && m <= vlo)) ? 1u : 0u;
    }
    unsigned int sc = cnt;
    #pragma unroll
    for (int off = 1; off < 64; off <<= 1){
        unsigned int o = __shfl_up(sc, off, 64);
        if (lane >= off) sc += o;
    }
    const unsigned int C = __shfl(sc, 63, 64);
    unsigned int pos = sc - cnt;

    __shared__ unsigned long long cand[4][CAPW];
    const bool fast = (C <= CAPW);
    if (fast){
        #pragma unroll
        for (int i = 0; i < 64; i++){
            const unsigned int m = (unsigned int)(i*64 + lane);
            if (k32[i] < vhi || (k32[i] == vhi && m <= vlo)){
                cand[wv][pos++] = (((unsigned long long)k32[i]) << 12) | (unsigned long long)m;
            }
        }
    }
    __syncthreads();   // single barrier: LDS visibility (all threads reach it)
    if (fast){
        for (unsigned int i = lane; i < C; i += 64){
            unsigned long long mk = cand[wv][i];
            unsigned int rank = 0;
            for (unsigned int j = 0; j < C; j++) rank += (cand[wv][j] < mk) ? 1u : 0u;
            if (rank < K_) knn[(size_t)p*K_ + rank] = (int)(mk & 0xFFFull);
        }
    } else {
        // correctness-only fallback (not expected): 32 rounds of wave-min extraction
        unsigned long long removed = 0ull;
        for (int it = 0; it < K_; it++){
            unsigned int bk = 0xFFFFFFFFu; unsigned int bi = 0;
            #pragma unroll
            for (int i = 0; i < 64; i++){
                if (!((removed >> i) & 1ull) && k32[i] < bk){ bk = k32[i]; bi = (unsigned int)i; }
            }
            unsigned long long mm =
                (((unsigned long long)bk) << 12) | (unsigned long long)(bi*64u + (unsigned int)lane);
            unsigned long long red = mm;
            #pragma unroll
            for (int off = 32; off; off >>= 1){
                unsigned long long o = __shfl_xor(red, off, 64);
                red = o < red ? o : red;
            }
            if (lane == 0) knn[(size_t)p*K_ + it] = (int)(red & 0xFFFull);
            if (mm == red) removed |= (1ull << bi);
        }
    }
}

// ---------------- generic MFMA GEMM: Y = epilogue(X(M,Kin) * W(O,Kin)^T) ----------------
// MODE 0: bias by 256-col range (e0|e1|e2) -> bf16 Y
// MODE 1: *scale(bn)+shift, relu -> bf16 Y   (e0=scale base, e1=shift)
// MODE 2: +bias(e0) + residual featA, write fp32 out transposed (B,C,N)
template<int MODE>
__global__ __launch_bounds__(256) void k_gemm(
    const unsigned short* __restrict__ X, int ldx,
    const unsigned short* __restrict__ W, int Kin,
    const float* __restrict__ e0, const float* __restrict__ e1, const float* __restrict__ e2,
    unsigned short* __restrict__ Y, int ldy,
    const float* __restrict__ resid, float* __restrict__ out)
{
    const int wid = threadIdx.x >> 6, lane = threadIdx.x & 63;
    const int lr = lane & 15, lg = lane >> 4;
    const int mw = blockIdx.x * 128 + wid * 32;
    const int cn = blockIdx.y * 64;
    f32x4 acc[2][4] = {};
    const unsigned short* xr0 = X + (size_t)(mw + lr) * ldx;
    const unsigned short* xr1 = xr0 + (size_t)16 * ldx;
    const unsigned short* wr0 = W + (size_t)(cn + lr) * Kin;
    for (int k0 = 0; k0 < Kin; k0 += 32){
        const int k = k0 + lg*8;
        bf16x8 a0 = *(const bf16x8*)(xr0 + k);
        bf16x8 a1 = *(const bf16x8*)(xr1 + k);
        #pragma unroll
        for (int ni = 0; ni < 4; ni++){
            bf16x8 bf = *(const bf16x8*)(wr0 + (size_t)ni*16*Kin + k);
            acc[0][ni] = __builtin_amdgcn_mfma_f32_16x16x32_bf16(a0, bf, acc[0][ni], 0, 0, 0);
            acc[1][ni] = __builtin_amdgcn_mfma_f32_16x16x32_bf16(a1, bf, acc[1][ni], 0, 0, 0);
        }
    }
    #pragma unroll
    for (int mi = 0; mi < 2; mi++){
        const int pbase = mw + mi*16 + lg*4;
        #pragma unroll
        for (int ni = 0; ni < 4; ni++){
            const int o = cn + ni*16 + lr;
            if (MODE == 0){
                const float* bp = (o < 256) ? e0 : ((o < 512) ? e1 : e2);
                float bias = bp[o & 255];
                #pragma unroll
                for (int r = 0; r < 4; r++)
                    Y[(size_t)(pbase + r)*ldy + o] = f2bf(acc[mi][ni][r] + bias);
            } else if (MODE == 1){
                float sc = e0[o] * 0.9999950000374997f;   // rsqrt(1+1e-5)*bn_g
                float sh = e1[o];
                #pragma unroll
                for (int r = 0; r < 4; r++){
                    float vv = fmaf(acc[mi][ni][r], sc, sh);
                    Y[(size_t)(pbase + r)*ldy + o] = f2bf(fmaxf(vv, 0.f));
                }
            } else {
                float bias = e0[o];
                const int b = pbase >> 12, nn = pbase & 4095;
                const size_t adr = ((size_t)b*C_ + o)*N_ + nn;
                f32x4 rv = *(const f32x4*)(resid + adr);
                f32x4 ov;
                #pragma unroll
                for (int r = 0; r < 4; r++) ov[r] = acc[mi][ni][r] + bias + rv[r];
                *(f32x4*)(out + adr) = ov;
            }
        }
    }
}

// ---------------- dual-path neighbor attention, one wave per point ----------------
// QQ: (8192,512) cols 0-255=q_s, 256-511=q_d ; KVD: (8192,768) cols 0-255=k_s, 256-511=v, 512-767=k_d
__global__ __launch_bounds__(256) void k_attn(
    const unsigned short* __restrict__ QQ, const unsigned short* __restrict__ KVD,
    const int* __restrict__ KNN,
    const float* __restrict__ lnsw, const float* __restrict__ lnsb,
    const float* __restrict__ lndw, const float* __restrict__ lndb,
    unsigned short* __restrict__ F)
{
    __shared__ float qs_l[4][256], qd_l[4][256];
    __shared__ float ws_l[4][8][32], wd_l[4][8][32];
    __shared__ int idx_l[4][32];
    const int wid = threadIdx.x >> 6, lane = threadIdx.x & 63;
    const int p = blockIdx.x*4 + wid;
    const int b = p >> 12;
    {
        ushort4_t qv = *(const ushort4_t*)(QQ + (size_t)p*512 + lane*4);
        ushort4_t dv = *(const ushort4_t*)(QQ + (size_t)p*512 + 256 + lane*4);
        #pragma unroll
        for (int j = 0; j < 4; j++){
            qs_l[wid][lane*4+j] = bf2f(qv[j]);
            qd_l[wid][lane*4+j] = bf2f(dv[j]);
        }
        if (lane < 32) idx_l[wid][lane] = KNN[(size_t)p*K_ + lane];
    }
    __syncthreads();
    const int kk = lane & 31, hg = lane >> 5;
    {
        const int nbr = idx_l[wid][kk];
        const unsigned short* base = KVD + ((size_t)(b<<12) + nbr)*768;
        const unsigned short* krow = base;
        const unsigned short* drow = base + 512;
        #pragma unroll
        for (int j = 0; j < 4; j++){
            const int h = hg*4 + j;
            const float* qs_h = &qs_l[wid][h*32];
            const float* qd_h = &qd_l[wid][h*32];
            const bf16x8* kr = (const bf16x8*)(krow + h*32);
            const bf16x8* dr = (const bf16x8*)(drow + h*32);
            float s = 0.f, dd = 0.f;
            #pragma unroll
            for (int c8 = 0; c8 < 4; c8++){
                bf16x8 kv = kr[c8], dvv = dr[c8];
                #pragma unroll
                for (int e = 0; e < 8; e++){
                    int d = c8*8 + e;
                    s = fmaf(qs_h[d], bf2f((unsigned short)kv[e]), s);
                    float df = qd_h[d] - bf2f((unsigned short)dvv[e]);
                    dd = fmaf(df, df, dd);
                }
            }
            float sim = s * 0.17677669529663687f;   // 1/sqrt(32)
            float dist = sqrtf(dd);
            float m1 = sim, m2 = dist;
            #pragma unroll
            for (int off = 1; off < 32; off <<= 1){
                m1 = fmaxf(m1, __shfl_xor(m1, off, 64));
                m2 = fmaxf(m2, __shfl_xor(m2, off, 64));
            }
            float e1v = __expf(sim - m1);
            float e2v = __expf(dist - m2);
            float s1 = e1v, s2 = e2v;
            #pragma unroll
            for (int off = 1; off < 32; off <<= 1){
                s1 += __shfl_xor(s1, off, 64);
                s2 += __shfl_xor(s2, off, 64);
            }
            ws_l[wid][h][kk] = e1v / s1;
            wd_l[wid][h][kk] = e2v / s2;
        }
    }
    __syncthreads();
    const int d = kk;
    float cs[4] = {0,0,0,0}, cd[4] = {0,0,0,0};
    for (int t = 0; t < 32; t++){
        const int nbr = idx_l[wid][t];
        const unsigned short* vrow = KVD + ((size_t)(b<<12) + nbr)*768 + 256;
        #pragma unroll
        for (int j = 0; j < 4; j++){
            const int h = hg*4 + j;
            float vf = bf2f(vrow[h*32 + d]);
            cs[j] = fmaf(ws_l[wid][h][t], vf, cs[j]);
            cd[j] = fmaf(wd_l[wid][h][t], vf, cd[j]);
        }
    }
    float s1 = 0.f, q1 = 0.f, s2 = 0.f, q2 = 0.f;
    #pragma unroll
    for (int j = 0; j < 4; j++){
        s1 += cs[j]; q1 = fmaf(cs[j], cs[j], q1);
        s2 += cd[j]; q2 = fmaf(cd[j], cd[j], q2);
    }
    #pragma unroll
    for (int off = 1; off < 64; off <<= 1){
        s1 += __shfl_xor(s1, off, 64); q1 += __shfl_xor(q1, off, 64);
        s2 += __shfl_xor(s2, off, 64); q2 += __shfl_xor(q2, off, 64);
    }
    float m1 = s1*(1.f/256.f), m2 = s2*(1.f/256.f);
    float r1 = rsqrtf(q1*(1.f/256.f) - m1*m1 + 1e-5f);
    float r2 = rsqrtf(q2*(1.f/256.f) - m2*m2 + 1e-5f);
    unsigned short* frow = F + (size_t)p*768;
    #pragma unroll
    for (int j = 0; j < 4; j++){
        int c = (hg*4 + j)*32 + d;
        frow[256 + c] = f2bf((cs[j]-m1)*r1*lnsw[c] + lnsb[c]);
        frow[512 + c] = f2bf((cd[j]-m2)*r2*lndw[c] + lndb[c]);
    }
}

extern "C" void kernel_launch(void* const* d_in, const int* in_sizes, int n_in,
                              void* d_out, int out_size, void* d_ws, size_t ws_size,
                              hipStream_t stream)
{
    const float* xyzA   = (const float*)d_in[0];
    const float* xyzB   = (const float*)d_in[1];
    const float* featA  = (const float*)d_in[2];
    const float* featB  = (const float*)d_in[3];
    const float* ln_in_w= (const float*)d_in[4];
    const float* ln_in_b= (const float*)d_in[5];
    const float* wq  = (const float*)d_in[6];
    const float* bq  = (const float*)d_in[7];
    const float* wk  = (const float*)d_in[8];
    const float* bk  = (const float*)d_in[9];
    const float* wv  = (const float*)d_in[10];
    const float* bv  = (const float*)d_in[11];
    const float* wqd = (const float*)d_in[12];
    const float* bqd = (const float*)d_in[13];
    const float* wkd = (const float*)d_in[14];
    const float* bkd = (const float*)d_in[15];
    const float* lnsw = (const float*)d_in[16];
    const float* lnsb = (const float*)d_in[17];
    const float* lndw = (const float*)d_in[18];
    const float* lndb = (const float*)d_in[19];
    const float* fw1 = (const float*)d_in[20];
    const float* bng = (const float*)d_in[21];
    const float* bnb = (const float*)d_in[22];
    const float* fw2 = (const float*)d_in[23];
    const float* fb2 = (const float*)d_in[24];
    float* out = (float*)d_out;
    char* ws = (char*)d_ws;

    unsigned short* F    = (unsigned short*)(ws + 0);          // 8192*768 bf16
    unsigned short* XBT  = (unsigned short*)(ws + 12582912);   // 8192*256
    unsigned short* QQ   = (unsigned short*)(ws + 16777216);   // 8192*512
    unsigned short* KVD  = (unsigned short*)(ws + 25165824);   // 8192*768
    unsigned short* Y1   = (unsigned short*)(ws + 37748736);   // 8192*512
    int*            KNNi = (int*)(ws + 46137344);              // 8192*32
    float*          STATS= (float*)(ws + 47185920);            // 8192*2
    unsigned short* Wb   = (unsigned short*)(ws + 47251456);   // 851968 bf16
    unsigned short* WQcat = Wb;                // 512x256
    unsigned short* WKVD  = Wb + 131072;       // 768x256
    unsigned short* W1b   = Wb + 327680;       // 512x768
    unsigned short* W2b   = Wb + 720896;       // 256x512

    k_cvt_all<<<3328, 256, 0, stream>>>(wq, wqd, wk, wv, wkd, fw1, fw2, Wb);

    k_ln_stats<<<128, 256, 0, stream>>>(featA, STATS);
    k_transpose<1><<<dim3(64,4,2), 256, 0, stream>>>(featA, F, 768, STATS, ln_in_w, ln_in_b);
    k_transpose<0><<<dim3(64,4,2), 256, 0, stream>>>(featB, XBT, 256, nullptr, nullptr, nullptr);
    k_knn<<<2048, 256, 0, stream>>>(xyzA, xyzB, KNNi);

    k_gemm<0><<<dim3(64,8), 256, 0, stream>>>(F,   768, WQcat, 256, bq, bqd, nullptr, QQ, 512, nullptr, nullptr);
    k_gemm<0><<<dim3(64,12), 256, 0, stream>>>(XBT, 256, WKVD, 256, bk, bv, bkd, KVD, 768, nullptr, nullptr);

    k_attn<<<2048, 256, 0, stream>>>(QQ, KVD, KNNi, lnsw, lnsb, lndw, lndb, F);

    k_gemm<1><<<dim3(64,8), 256, 0, stream>>>(F,  768, W1b, 768, bng, bnb, nullptr, Y1, 512, nullptr, nullptr);
    k_gemm<2><<<dim3(64,4), 256, 0, stream>>>(Y1, 512, W2b, 512, fb2, nullptr, nullptr, nullptr, 0, featA, out);
}

// Round 5
// 217.696 us; speedup vs baseline: 1.6168x; 1.1661x over previous
//
#include <hip/hip_runtime.h>
#include <hip/hip_bf16.h>
#include <math.h>

#define B_ 2
#define N_ 4096
#define C_ 256
#define H_ 8
#define K_ 32
#define NP_ (B_*N_)
#define CAPW 256

typedef __attribute__((ext_vector_type(8))) short bf16x8;
typedef __attribute__((ext_vector_type(4))) float f32x4;
typedef __attribute__((ext_vector_type(4))) unsigned short ushort4_t;

__device__ __forceinline__ float bf2f(unsigned short v){
    union { unsigned int u; float f; } x; x.u = ((unsigned int)v) << 16; return x.f;
}
__device__ __forceinline__ unsigned short f2bf(float f){
    union { float f; unsigned int u; } x; x.f = f;
    return (unsigned short)((x.u + 0x7FFFu + ((x.u >> 16) & 1u)) >> 16);
}

// ---------------- batched weight fp32 -> bf16 into contiguous Wbase ----------------
__global__ __launch_bounds__(256) void k_cvt_all(
    const float* __restrict__ s0, const float* __restrict__ s1,
    const float* __restrict__ s2, const float* __restrict__ s3,
    const float* __restrict__ s4, const float* __restrict__ s5,
    const float* __restrict__ s6, unsigned short* __restrict__ dst)
{
    int i = blockIdx.x*256 + threadIdx.x;   // 3328*256 = 851968 exactly
    float v;
    if (i < 327680){
        int seg = i >> 16, off = i & 65535;
        const float* s = (seg==0)?s0:(seg==1)?s1:(seg==2)?s2:(seg==3)?s3:s4;
        v = s[off];
    } else if (i < 720896){
        v = s5[i - 327680];
    } else {
        v = s6[i - 720896];
    }
    dst[i] = f2bf(v);
}

// ---------------- LN stats over C for featA (B,C,N) ----------------
__global__ __launch_bounds__(256) void k_ln_stats(const float* __restrict__ fa, float* __restrict__ stats){
    __shared__ float part[2][4][64];
    const int lane = threadIdx.x & 63, wq = threadIdx.x >> 6;
    const int pbase = blockIdx.x * 64;
    const int p = pbase + lane;
    const int b = p >> 12, n = p & 4095;
    const float* base = fa + (size_t)b*C_*N_ + n;
    float s = 0.f, sq = 0.f;
    #pragma unroll 8
    for (int i = 0; i < 64; i++){
        float x = base[(size_t)(wq*64 + i)*N_];
        s += x; sq = fmaf(x, x, sq);
    }
    part[0][wq][lane] = s; part[1][wq][lane] = sq;
    __syncthreads();
    if (threadIdx.x < 64){
        int l = threadIdx.x;
        float S = part[0][0][l]+part[0][1][l]+part[0][2][l]+part[0][3][l];
        float Q = part[1][0][l]+part[1][1][l]+part[1][2][l]+part[1][3][l];
        float m = S*(1.f/256.f);
        float var = Q*(1.f/256.f) - m*m;
        stats[2*(pbase+l)]   = m;
        stats[2*(pbase+l)+1] = rsqrtf(var + 1e-5f);
    }
}

// ---------------- transpose (B,C,N)->(B,N,C) bf16, optional LN ----------------
template<int DO_LN>
__global__ __launch_bounds__(256) void k_transpose(const float* __restrict__ src,
                            unsigned short* __restrict__ dst, int dstStride,
                            const float* __restrict__ stats,
                            const float* __restrict__ lnw, const float* __restrict__ lnb){
    __shared__ float tile[64][65];
    const int b = blockIdx.z;
    const int n0 = blockIdx.x*64, c0 = blockIdx.y*64;
    const int tx = threadIdx.x & 63, ty = threadIdx.x >> 6;
    const float* sp = src + (size_t)b*C_*N_;
    #pragma unroll
    for (int i = 0; i < 16; i++){
        int cr = ty + i*4;
        tile[cr][tx] = sp[(size_t)(c0+cr)*N_ + n0 + tx];
    }
    __syncthreads();
    const int c = c0 + tx;
    #pragma unroll
    for (int i = 0; i < 16; i++){
        int nr = ty + i*4;
        int n = n0 + nr;
        float x = tile[tx][nr];
        int p = (b<<12) + n;
        if (DO_LN){
            float mean = stats[2*p], rstd = stats[2*p+1];
            x = (x - mean)*rstd*lnw[c] + lnb[c];
        }
        dst[(size_t)p*dstStride + c] = f2bf(x);
    }
}

// ---------------- KNN: one query per wave (unchanged from round 4) ----------
__global__ __launch_bounds__(256) void k_knn(const float* __restrict__ xyzA,
        const float* __restrict__ xyzB, int* __restrict__ knn){
    const int wv = threadIdx.x >> 6, lane = threadIdx.x & 63;
    const int p = blockIdx.x*4 + wv;
    const int b = p >> 12;
    const float* pb = xyzB + (size_t)b*N_*3;
    const float* pa = xyzA + (size_t)p*3;
    const float ax = pa[0], ay = pa[1], az = pa[2];
    const float sa = ax*ax + ay*ay + az*az;

    unsigned int k32[64];
    unsigned int bestk = 0xFFFFFFFFu; unsigned int besti = 0;
    #pragma unroll
    for (int i = 0; i < 64; i++){
        const int m = i*64 + lane;
        float bx = pb[m*3], by = pb[m*3+1], bz = pb[m*3+2];
        float d2 = (sa + bx*bx + by*by + bz*bz) - 2.f*(ax*bx + ay*by + az*bz);
        union { float f; unsigned int u; } cv; cv.f = d2;
        unsigned int u = cv.u ^ (0x80000000u | (unsigned int)((int)cv.u >> 31));
        k32[i] = u;
        if (u < bestk){ bestk = u; besti = (unsigned int)i; }
    }
    const unsigned long long mn =
        (((unsigned long long)bestk) << 12) | (unsigned long long)(besti*64u + (unsigned int)lane);

    unsigned int rk = 0;
    for (int j = 0; j < 64; j++){
        unsigned long long o = __shfl(mn, j, 64);
        rk += (o < mn) ? 1u : 0u;
    }
    unsigned long long sel = (rk == 31u) ? mn : ~0ull;
    #pragma unroll
    for (int off = 32; off; off >>= 1){
        unsigned long long o = __shfl_xor(sel, off, 64);
        sel = o < sel ? o : sel;
    }
    const unsigned long long v = sel;
    const unsigned int vhi = (unsigned int)(v >> 12);
    const unsigned int vlo = (unsigned int)(v & 0xFFFull);

    unsigned int cnt = 0;
    #pragma unroll
    for (int i = 0; i < 64; i++){
        const unsigned int m = (unsigned int)(i*64 + lane);
        cnt += (k32[i] < vhi || (k32[i] == vhi && m <= vlo)) ? 1u : 0u;
    }
    unsigned int sc = cnt;
    #pragma unroll
    for (int off = 1; off < 64; off <<= 1){
        unsigned int o = __shfl_up(sc, off, 64);
        if (lane >= off) sc += o;
    }
    const unsigned int C = __shfl(sc, 63, 64);
    unsigned int pos = sc - cnt;

    __shared__ unsigned long long cand[4][CAPW];
    const bool fast = (C <= CAPW);
    if (fast){
        #pragma unroll
        for (int i = 0; i < 64; i++){
            const unsigned int m = (unsigned int)(i*64 + lane);
            if (k32[i] < vhi || (k32[i] == vhi && m <= vlo)){
                cand[wv][pos++] = (((unsigned long long)k32[i]) << 12) | (unsigned long long)m;
            }
        }
    }
    __syncthreads();
    if (fast){
        for (unsigned int i = lane; i < C; i += 64){
            unsigned long long mk = cand[wv][i];
            unsigned int rank = 0;
            for (unsigned int j = 0; j < C; j++) rank += (cand[wv][j] < mk) ? 1u : 0u;
            if (rank < K_) knn[(size_t)p*K_ + rank] = (int)(mk & 0xFFFull);
        }
    } else {
        unsigned long long removed = 0ull;
        for (int it = 0; it < K_; it++){
            unsigned int bk = 0xFFFFFFFFu; unsigned int bi = 0;
            #pragma unroll
            for (int i = 0; i < 64; i++){
                if (!((removed >> i) & 1ull) && k32[i] < bk){ bk = k32[i]; bi = (unsigned int)i; }
            }
            unsigned long long mm =
                (((unsigned long long)bk) << 12) | (unsigned long long)(bi*64u + (unsigned int)lane);
            unsigned long long red = mm;
            #pragma unroll
            for (int off = 32; off; off >>= 1){
                unsigned long long o = __shfl_xor(red, off, 64);
                red = o < red ? o : red;
            }
            if (lane == 0) knn[(size_t)p*K_ + it] = (int)(red & 0xFFFull);
            if (mm == red) removed |= (1ull << bi);
        }
    }
}

// ---------------- generic MFMA GEMM (unchanged) ----------------
template<int MODE>
__global__ __launch_bounds__(256) void k_gemm(
    const unsigned short* __restrict__ X, int ldx,
    const unsigned short* __restrict__ W, int Kin,
    const float* __restrict__ e0, const float* __restrict__ e1, const float* __restrict__ e2,
    unsigned short* __restrict__ Y, int ldy,
    const float* __restrict__ resid, float* __restrict__ out)
{
    const int wid = threadIdx.x >> 6, lane = threadIdx.x & 63;
    const int lr = lane & 15, lg = lane >> 4;
    const int mw = blockIdx.x * 128 + wid * 32;
    const int cn = blockIdx.y * 64;
    f32x4 acc[2][4] = {};
    const unsigned short* xr0 = X + (size_t)(mw + lr) * ldx;
    const unsigned short* xr1 = xr0 + (size_t)16 * ldx;
    const unsigned short* wr0 = W + (size_t)(cn + lr) * Kin;
    for (int k0 = 0; k0 < Kin; k0 += 32){
        const int k = k0 + lg*8;
        bf16x8 a0 = *(const bf16x8*)(xr0 + k);
        bf16x8 a1 = *(const bf16x8*)(xr1 + k);
        #pragma unroll
        for (int ni = 0; ni < 4; ni++){
            bf16x8 bf = *(const bf16x8*)(wr0 + (size_t)ni*16*Kin + k);
            acc[0][ni] = __builtin_amdgcn_mfma_f32_16x16x32_bf16(a0, bf, acc[0][ni], 0, 0, 0);
            acc[1][ni] = __builtin_amdgcn_mfma_f32_16x16x32_bf16(a1, bf, acc[1][ni], 0, 0, 0);
        }
    }
    #pragma unroll
    for (int mi = 0; mi < 2; mi++){
        const int pbase = mw + mi*16 + lg*4;
        #pragma unroll
        for (int ni = 0; ni < 4; ni++){
            const int o = cn + ni*16 + lr;
            if (MODE == 0){
                const float* bp = (o < 256) ? e0 : ((o < 512) ? e1 : e2);
                float bias = bp[o & 255];
                #pragma unroll
                for (int r = 0; r < 4; r++)
                    Y[(size_t)(pbase + r)*ldy + o] = f2bf(acc[mi][ni][r] + bias);
            } else if (MODE == 1){
                float sc = e0[o] * 0.9999950000374997f;   // rsqrt(1+1e-5)*bn_g
                float sh = e1[o];
                #pragma unroll
                for (int r = 0; r < 4; r++){
                    float vv = fmaf(acc[mi][ni][r], sc, sh);
                    Y[(size_t)(pbase + r)*ldy + o] = f2bf(fmaxf(vv, 0.f));
                }
            } else {
                float bias = e0[o];
                const int b = pbase >> 12, nn = pbase & 4095;
                const size_t adr = ((size_t)b*C_ + o)*N_ + nn;
                f32x4 rv = *(const f32x4*)(resid + adr);
                f32x4 ov;
                #pragma unroll
                for (int r = 0; r < 4; r++) ov[r] = acc[mi][ni][r] + bias + rv[r];
                *(f32x4*)(out + adr) = ov;
            }
        }
    }
}

// ---------------- dual-path neighbor attention: 2 waves per point (head halves) ----
// QQ: (8192,512) cols 0-255=q_s, 256-511=q_d ; KVD: (8192,768) = k_s|v|k_d
// Block = 256 thr = 4 waves = 2 points x 2 head-halves. Batch->XCD grouping via bid parity.
__global__ __launch_bounds__(256) void k_attn(
    const unsigned short* __restrict__ QQ, const unsigned short* __restrict__ KVD,
    const int* __restrict__ KNN,
    const float* __restrict__ lnsw, const float* __restrict__ lnsb,
    const float* __restrict__ lndw, const float* __restrict__ lndb,
    unsigned short* __restrict__ F)
{
    __shared__ float q_l[2][2][2][128];     // [ps][wh][sim/dis][dim]
    __shared__ float w_l[2][2][2][4][32];   // [ps][wh][path][h_local][k]
    __shared__ int   idx_l[2][32];
    __shared__ float part_l[2][2][4];

    const int tid = threadIdx.x;
    const int wid = tid >> 6, lane = tid & 63;
    const int ps = wid >> 1, wh = wid & 1;
    const int bid = blockIdx.x;                    // 4096 blocks
    const int pair = ((bid & 1) << 11) | (bid >> 1);   // even bid -> batch 0 XCDs
    const int p = pair*2 + ps;
    const int b = p >> 12;

    // ---- stage: q half (sim+dis) to LDS, knn ids ----
    {
        const unsigned short* qrow = QQ + (size_t)p*512 + wh*128 + lane*2;
        unsigned int us = *(const unsigned int*)qrow;
        unsigned int ud = *(const unsigned int*)(qrow + 256);
        q_l[ps][wh][0][lane*2]   = bf2f((unsigned short)(us & 0xffff));
        q_l[ps][wh][0][lane*2+1] = bf2f((unsigned short)(us >> 16));
        q_l[ps][wh][1][lane*2]   = bf2f((unsigned short)(ud & 0xffff));
        q_l[ps][wh][1][lane*2+1] = bf2f((unsigned short)(ud >> 16));
        if (wh == 0 && lane < 32) idx_l[ps][lane] = KNN[(size_t)p*K_ + lane];
    }
    __syncthreads();

    // ---- QK + dist + softmax: lane = (hh, kk); 4 local heads via j=0,1 ----
    const int hh = lane >> 5, kk = lane & 31;
    {
        const int nbr = idx_l[ps][kk];
        const unsigned short* rowb = KVD + (size_t)((b<<12) + nbr)*768;
        bf16x8 kx[2][4], dx[2][4];
        #pragma unroll
        for (int j = 0; j < 2; j++){
            const int h = wh*4 + j*2 + hh;
            const bf16x8* kr = (const bf16x8*)(rowb + h*32);
            const bf16x8* dr = (const bf16x8*)(rowb + 512 + h*32);
            #pragma unroll
            for (int c = 0; c < 4; c++){ kx[j][c] = kr[c]; dx[j][c] = dr[c]; }
        }
        #pragma unroll
        for (int j = 0; j < 2; j++){
            const int hl = j*2 + hh;
            const float* qs = &q_l[ps][wh][0][hl*32];
            const float* qd = &q_l[ps][wh][1][hl*32];
            float s = 0.f, dd = 0.f;
            #pragma unroll
            for (int c = 0; c < 4; c++){
                #pragma unroll
                for (int e = 0; e < 8; e++){
                    const int d = c*8 + e;
                    s = fmaf(qs[d], bf2f((unsigned short)kx[j][c][e]), s);
                    float df = qd[d] - bf2f((unsigned short)dx[j][c][e]);
                    dd = fmaf(df, df, dd);
                }
            }
            float sim = s * 0.17677669529663687f;   // 1/sqrt(32)
            float dist = sqrtf(dd);
            float m1 = sim, m2 = dist;
            #pragma unroll
            for (int off = 1; off < 32; off <<= 1){
                m1 = fmaxf(m1, __shfl_xor(m1, off, 64));
                m2 = fmaxf(m2, __shfl_xor(m2, off, 64));
            }
            float e1v = __expf(sim - m1);
            float e2v = __expf(dist - m2);
            float s1 = e1v, s2 = e2v;
            #pragma unroll
            for (int off = 1; off < 32; off <<= 1){
                s1 += __shfl_xor(s1, off, 64);
                s2 += __shfl_xor(s2, off, 64);
            }
            w_l[ps][wh][0][hl][kk] = e1v / s1;
            w_l[ps][wh][1][hl][kk] = e2v / s2;
        }
    }
    // wave-local LDS produce->consume (lockstep wave + compiler lgkmcnt): no barrier

    // ---- PV: lane = (tq=lane>>4 row-quad, c=lane&15 chunk of 8 dims) ----
    const int tq = lane >> 4, c = lane & 15;
    float cs[8] = {0,0,0,0,0,0,0,0}, cd[8] = {0,0,0,0,0,0,0,0};
    {
        const unsigned short* vbase = KVD + 256 + wh*128 + c*8;
        const int hl = c >> 2;
        int t = tq;
        int nbr = idx_l[ps][t];
        bf16x8 cur = *(const bf16x8*)(vbase + (size_t)((b<<12) + nbr)*768);
        #pragma unroll
        for (int i = 0; i < 8; i++){
            bf16x8 nxt;
            if (i < 7){
                int nn = idx_l[ps][t + 4];
                nxt = *(const bf16x8*)(vbase + (size_t)((b<<12) + nn)*768);
            }
            const float wsv = w_l[ps][wh][0][hl][t];
            const float wdv = w_l[ps][wh][1][hl][t];
            #pragma unroll
            for (int e = 0; e < 8; e++){
                float vf = bf2f((unsigned short)cur[e]);
                cs[e] = fmaf(wsv, vf, cs[e]);
                cd[e] = fmaf(wdv, vf, cd[e]);
            }
            cur = nxt; t += 4;
        }
    }
    // reduce across the 4 row-quads (xor 16, 32)
    #pragma unroll
    for (int e = 0; e < 8; e++){
        cs[e] += __shfl_xor(cs[e], 16, 64); cs[e] += __shfl_xor(cs[e], 32, 64);
        cd[e] += __shfl_xor(cd[e], 16, 64); cd[e] += __shfl_xor(cd[e], 32, 64);
    }
    // half (128-dim) LN partials: sum over 16 chunks (xor 1..8 within c-group)
    float s1 = 0.f, q1 = 0.f, s2 = 0.f, q2 = 0.f;
    #pragma unroll
    for (int e = 0; e < 8; e++){
        s1 += cs[e]; q1 = fmaf(cs[e], cs[e], q1);
        s2 += cd[e]; q2 = fmaf(cd[e], cd[e], q2);
    }
    #pragma unroll
    for (int off = 1; off < 16; off <<= 1){
        s1 += __shfl_xor(s1, off, 64); q1 += __shfl_xor(q1, off, 64);
        s2 += __shfl_xor(s2, off, 64); q2 += __shfl_xor(q2, off, 64);
    }
    if (lane == 0){
        part_l[ps][wh][0] = s1; part_l[ps][wh][1] = q1;
        part_l[ps][wh][2] = s2; part_l[ps][wh][3] = q2;
    }
    __syncthreads();
    const float S1 = s1 + part_l[ps][wh^1][0];
    const float Q1 = q1 + part_l[ps][wh^1][1];
    const float S2 = s2 + part_l[ps][wh^1][2];
    const float Q2 = q2 + part_l[ps][wh^1][3];
    const float m1 = S1*(1.f/256.f), m2 = S2*(1.f/256.f);
    const float r1 = rsqrtf(Q1*(1.f/256.f) - m1*m1 + 1e-5f);
    const float r2 = rsqrtf(Q2*(1.f/256.f) - m2*m2 + 1e-5f);

    if (tq == 0){
        bf16x8 ob;
        #pragma unroll
        for (int e = 0; e < 8; e++){
            const int cg = wh*128 + c*8 + e;
            ob[e] = (short)f2bf((cs[e]-m1)*r1*lnsw[cg] + lnsb[cg]);
        }
        *(bf16x8*)(F + (size_t)p*768 + 256 + wh*128 + c*8) = ob;
    } else if (tq == 1){
        bf16x8 ob;
        #pragma unroll
        for (int e = 0; e < 8; e++){
            const int cg = wh*128 + c*8 + e;
            ob[e] = (short)f2bf((cd[e]-m2)*r2*lndw[cg] + lndb[cg]);
        }
        *(bf16x8*)(F + (size_t)p*768 + 512 + wh*128 + c*8) = ob;
    }
}

extern "C" void kernel_launch(void* const* d_in, const int* in_sizes, int n_in,
                              void* d_out, int out_size, void* d_ws, size_t ws_size,
                              hipStream_t stream)
{
    const float* xyzA   = (const float*)d_in[0];
    const float* xyzB   = (const float*)d_in[1];
    const float* featA  = (const float*)d_in[2];
    const float* featB  = (const float*)d_in[3];
    const float* ln_in_w= (const float*)d_in[4];
    const float* ln_in_b= (const float*)d_in[5];
    const float* wq  = (const float*)d_in[6];
    const float* bq  = (const float*)d_in[7];
    const float* wk  = (const float*)d_in[8];
    const float* bk  = (const float*)d_in[9];
    const float* wv  = (const float*)d_in[10];
    const float* bv  = (const float*)d_in[11];
    const float* wqd = (const float*)d_in[12];
    const float* bqd = (const float*)d_in[13];
    const float* wkd = (const float*)d_in[14];
    const float* bkd = (const float*)d_in[15];
    const float* lnsw = (const float*)d_in[16];
    const float* lnsb = (const float*)d_in[17];
    const float* lndw = (const float*)d_in[18];
    const float* lndb = (const float*)d_in[19];
    const float* fw1 = (const float*)d_in[20];
    const float* bng = (const float*)d_in[21];
    const float* bnb = (const float*)d_in[22];
    const float* fw2 = (const float*)d_in[23];
    const float* fb2 = (const float*)d_in[24];
    float* out = (float*)d_out;
    char* ws = (char*)d_ws;

    unsigned short* F    = (unsigned short*)(ws + 0);          // 8192*768 bf16
    unsigned short* XBT  = (unsigned short*)(ws + 12582912);   // 8192*256
    unsigned short* QQ   = (unsigned short*)(ws + 16777216);   // 8192*512
    unsigned short* KVD  = (unsigned short*)(ws + 25165824);   // 8192*768
    unsigned short* Y1   = (unsigned short*)(ws + 37748736);   // 8192*512
    int*            KNNi = (int*)(ws + 46137344);              // 8192*32
    float*          STATS= (float*)(ws + 47185920);            // 8192*2
    unsigned short* Wb   = (unsigned short*)(ws + 47251456);   // 851968 bf16
    unsigned short* WQcat = Wb;                // 512x256
    unsigned short* WKVD  = Wb + 131072;       // 768x256
    unsigned short* W1b   = Wb + 327680;       // 512x768
    unsigned short* W2b   = Wb + 720896;       // 256x512

    k_cvt_all<<<3328, 256, 0, stream>>>(wq, wqd, wk, wv, wkd, fw1, fw2, Wb);

    k_ln_stats<<<128, 256, 0, stream>>>(featA, STATS);
    k_transpose<1><<<dim3(64,4,2), 256, 0, stream>>>(featA, F, 768, STATS, ln_in_w, ln_in_b);
    k_transpose<0><<<dim3(64,4,2), 256, 0, stream>>>(featB, XBT, 256, nullptr, nullptr, nullptr);
    k_knn<<<2048, 256, 0, stream>>>(xyzA, xyzB, KNNi);

    k_gemm<0><<<dim3(64,8), 256, 0, stream>>>(F,   768, WQcat, 256, bq, bqd, nullptr, QQ, 512, nullptr, nullptr);
    k_gemm<0><<<dim3(64,12), 256, 0, stream>>>(XBT, 256, WKVD, 256, bk, bv, bkd, KVD, 768, nullptr, nullptr);

    k_attn<<<4096, 256, 0, stream>>>(QQ, KVD, KNNi, lnsw, lnsb, lndw, lndb, F);

    k_gemm<1><<<dim3(64,8), 256, 0, stream>>>(F,  768, W1b, 768, bng, bnb, nullptr, Y1, 512, nullptr, nullptr);
    k_gemm<2><<<dim3(64,4), 256, 0, stream>>>(Y1, 512, W2b, 512, fb2, nullptr, nullptr, nullptr, 0, featA, out);
}

// Round 6
// 196.820 us; speedup vs baseline: 1.7883x; 1.1061x over previous
//
#include <hip/hip_runtime.h>
#include <hip/hip_bf16.h>
#include <math.h>

#define B_ 2
#define N_ 4096
#define C_ 256
#define H_ 8
#define K_ 32
#define NP_ (B_*N_)
#define CAPW 256

typedef __attribute__((ext_vector_type(8))) short bf16x8;
typedef __attribute__((ext_vector_type(4))) float f32x4;
typedef __attribute__((ext_vector_type(4))) unsigned short ushort4_t;

__device__ __forceinline__ float bf2f(unsigned short v){
    union { unsigned int u; float f; } x; x.u = ((unsigned int)v) << 16; return x.f;
}
__device__ __forceinline__ unsigned short f2bf(float f){
    union { float f; unsigned int u; } x; x.f = f;
    return (unsigned short)((x.u + 0x7FFFu + ((x.u >> 16) & 1u)) >> 16);
}
__device__ __forceinline__ unsigned int mono(float f){
    union { float f; unsigned int u; } x; x.f = f;
    return x.u ^ (0x80000000u | (unsigned int)((int)x.u >> 31));
}

// ---------------- batched weight fp32 -> bf16 into contiguous Wbase ----------------
__global__ __launch_bounds__(256) void k_cvt_all(
    const float* __restrict__ s0, const float* __restrict__ s1,
    const float* __restrict__ s2, const float* __restrict__ s3,
    const float* __restrict__ s4, const float* __restrict__ s5,
    const float* __restrict__ s6, unsigned short* __restrict__ dst)
{
    int i = blockIdx.x*256 + threadIdx.x;   // 3328*256 = 851968 exactly
    float v;
    if (i < 327680){
        int seg = i >> 16, off = i & 65535;
        const float* s = (seg==0)?s0:(seg==1)?s1:(seg==2)?s2:(seg==3)?s3:s4;
        v = s[off];
    } else if (i < 720896){
        v = s5[i - 327680];
    } else {
        v = s6[i - 720896];
    }
    dst[i] = f2bf(v);
}

// ---------------- pack xyzB -> (-2x,-2y,-2z,|p|^2) float4 ----------------
__global__ __launch_bounds__(256) void k_prep(const float* __restrict__ xyzB,
                                              f32x4* __restrict__ PB){
    int i = blockIdx.x*256 + threadIdx.x;   // 32 blocks -> 8192
    if (i < NP_){
        float x = xyzB[i*3], y = xyzB[i*3+1], z = xyzB[i*3+2];
        f32x4 o;
        o[0] = -2.f*x; o[1] = -2.f*y; o[2] = -2.f*z;
        o[3] = x*x + y*y + z*z;
        PB[i] = o;
    }
}

// ---------------- LN stats over C for featA (B,C,N) ----------------
__global__ __launch_bounds__(256) void k_ln_stats(const float* __restrict__ fa, float* __restrict__ stats){
    __shared__ float part[2][4][64];
    const int lane = threadIdx.x & 63, wq = threadIdx.x >> 6;
    const int pbase = blockIdx.x * 64;
    const int p = pbase + lane;
    const int b = p >> 12, n = p & 4095;
    const float* base = fa + (size_t)b*C_*N_ + n;
    float s = 0.f, sq = 0.f;
    #pragma unroll 8
    for (int i = 0; i < 64; i++){
        float x = base[(size_t)(wq*64 + i)*N_];
        s += x; sq = fmaf(x, x, sq);
    }
    part[0][wq][lane] = s; part[1][wq][lane] = sq;
    __syncthreads();
    if (threadIdx.x < 64){
        int l = threadIdx.x;
        float S = part[0][0][l]+part[0][1][l]+part[0][2][l]+part[0][3][l];
        float Q = part[1][0][l]+part[1][1][l]+part[1][2][l]+part[1][3][l];
        float m = S*(1.f/256.f);
        float var = Q*(1.f/256.f) - m*m;
        stats[2*(pbase+l)]   = m;
        stats[2*(pbase+l)+1] = rsqrtf(var + 1e-5f);
    }
}

// ---------------- transpose (B,C,N)->(B,N,C) bf16, optional LN ----------------
template<int DO_LN>
__global__ __launch_bounds__(256) void k_transpose(const float* __restrict__ src,
                            unsigned short* __restrict__ dst, int dstStride,
                            const float* __restrict__ stats,
                            const float* __restrict__ lnw, const float* __restrict__ lnb){
    __shared__ float tile[64][65];
    const int b = blockIdx.z;
    const int n0 = blockIdx.x*64, c0 = blockIdx.y*64;
    const int tx = threadIdx.x & 63, ty = threadIdx.x >> 6;
    const float* sp = src + (size_t)b*C_*N_;
    #pragma unroll
    for (int i = 0; i < 16; i++){
        int cr = ty + i*4;
        tile[cr][tx] = sp[(size_t)(c0+cr)*N_ + n0 + tx];
    }
    __syncthreads();
    const int c = c0 + tx;
    #pragma unroll
    for (int i = 0; i < 16; i++){
        int nr = ty + i*4;
        int n = n0 + nr;
        float x = tile[tx][nr];
        int p = (b<<12) + n;
        if (DO_LN){
            float mean = stats[2*p], rstd = stats[2*p+1];
            x = (x - mean)*rstd*lnw[c] + lnb[c];
        }
        dst[(size_t)p*dstStride + c] = f2bf(x);
    }
}

// ---------------- KNN: storage-free two-pass, one query per wave ----------------
// Pass1: lane-min over 64 candidates (1 float4 load + 3 FMA each). Threshold v =
// 32nd-smallest of the 64 lane minima (provably >= T32). Pass2: recompute, gather
// keys<=v to per-wave LDS (wave-local atomics, no barriers), exact rank, write.
__global__ __launch_bounds__(256) void k_knn(const float* __restrict__ xyzA,
        const f32x4* __restrict__ PB, int* __restrict__ knn){
    const int wv = threadIdx.x >> 6, lane = threadIdx.x & 63;
    const int p = blockIdx.x*4 + wv;
    const int b = p >> 12;
    const f32x4* pb = PB + ((size_t)b << 12);
    const float ax = xyzA[(size_t)p*3], ay = xyzA[(size_t)p*3+1], az = xyzA[(size_t)p*3+2];

    // pass 1: lane minimum
    unsigned long long mn = ~0ull;
    #pragma unroll 8
    for (int i = 0; i < 64; i++){
        const int m = i*64 + lane;
        f32x4 c = pb[m];
        float d = fmaf(ax, c[0], fmaf(ay, c[1], fmaf(az, c[2], c[3])));
        unsigned long long key = (((unsigned long long)mono(d)) << 12) | (unsigned int)m;
        mn = key < mn ? key : mn;
    }
    // rank of this lane's min among the wave's 64 minima (unique keys)
    unsigned int rk = 0;
    for (int j = 0; j < 64; j++){
        unsigned long long o = __shfl(mn, j, 64);
        rk += (o < mn) ? 1u : 0u;
    }
    unsigned long long sel = (rk == 31u) ? mn : ~0ull;
    #pragma unroll
    for (int off = 32; off; off >>= 1){
        unsigned long long o = __shfl_xor(sel, off, 64);
        sel = o < sel ? o : sel;
    }
    const unsigned long long v = sel;
    const unsigned int vhi = (unsigned int)(v >> 12);
    const unsigned int vlo = (unsigned int)(v & 0xFFFull);

    // pass 2: gather candidates (per-wave LDS, no cross-wave interaction)
    __shared__ unsigned long long cand[4][CAPW];
    __shared__ unsigned int cnt[4];
    if (lane == 0) cnt[wv] = 0u;
    #pragma unroll 8
    for (int i = 0; i < 64; i++){
        const int m = i*64 + lane;
        f32x4 c = pb[m];
        float d = fmaf(ax, c[0], fmaf(ay, c[1], fmaf(az, c[2], c[3])));
        unsigned int u = mono(d);
        if (u < vhi || (u == vhi && (unsigned int)m <= vlo)){
            unsigned int slot = atomicAdd(&cnt[wv], 1u);
            if (slot < CAPW)
                cand[wv][slot] = (((unsigned long long)u) << 12) | (unsigned int)m;
        }
    }
    const unsigned int C = cnt[wv];
    if (C <= CAPW){
        for (unsigned int i = lane; i < C; i += 64){
            unsigned long long mk = cand[wv][i];
            unsigned int rank = 0;
            for (unsigned int j = 0; j < C; j++) rank += (cand[wv][j] < mk) ? 1u : 0u;
            if (rank < K_) knn[(size_t)p*K_ + rank] = (int)(mk & 0xFFFull);
        }
    } else {
        // correctness-only fallback: ascending threshold walk (stateless, exact)
        unsigned long long last = 0ull;
        for (int it = 0; it < K_; it++){
            unsigned long long cm = ~0ull;
            #pragma unroll 4
            for (int i = 0; i < 64; i++){
                const int m = i*64 + lane;
                f32x4 c = pb[m];
                float d = fmaf(ax, c[0], fmaf(ay, c[1], fmaf(az, c[2], c[3])));
                unsigned long long key = (((unsigned long long)mono(d)) << 12) | (unsigned int)m;
                if (key > last && key < cm) cm = key;
            }
            #pragma unroll
            for (int off = 32; off; off >>= 1){
                unsigned long long o = __shfl_xor(cm, off, 64);
                cm = o < cm ? o : cm;
            }
            if (lane == 0) knn[(size_t)p*K_ + it] = (int)(cm & 0xFFFull);
            last = cm;
        }
    }
}

// ---------------- generic MFMA GEMM (unchanged) ----------------
template<int MODE>
__global__ __launch_bounds__(256) void k_gemm(
    const unsigned short* __restrict__ X, int ldx,
    const unsigned short* __restrict__ W, int Kin,
    const float* __restrict__ e0, const float* __restrict__ e1, const float* __restrict__ e2,
    unsigned short* __restrict__ Y, int ldy,
    const float* __restrict__ resid, float* __restrict__ out)
{
    const int wid = threadIdx.x >> 6, lane = threadIdx.x & 63;
    const int lr = lane & 15, lg = lane >> 4;
    const int mw = blockIdx.x * 128 + wid * 32;
    const int cn = blockIdx.y * 64;
    f32x4 acc[2][4] = {};
    const unsigned short* xr0 = X + (size_t)(mw + lr) * ldx;
    const unsigned short* xr1 = xr0 + (size_t)16 * ldx;
    const unsigned short* wr0 = W + (size_t)(cn + lr) * Kin;
    for (int k0 = 0; k0 < Kin; k0 += 32){
        const int k = k0 + lg*8;
        bf16x8 a0 = *(const bf16x8*)(xr0 + k);
        bf16x8 a1 = *(const bf16x8*)(xr1 + k);
        #pragma unroll
        for (int ni = 0; ni < 4; ni++){
            bf16x8 bf = *(const bf16x8*)(wr0 + (size_t)ni*16*Kin + k);
            acc[0][ni] = __builtin_amdgcn_mfma_f32_16x16x32_bf16(a0, bf, acc[0][ni], 0, 0, 0);
            acc[1][ni] = __builtin_amdgcn_mfma_f32_16x16x32_bf16(a1, bf, acc[1][ni], 0, 0, 0);
        }
    }
    #pragma unroll
    for (int mi = 0; mi < 2; mi++){
        const int pbase = mw + mi*16 + lg*4;
        #pragma unroll
        for (int ni = 0; ni < 4; ni++){
            const int o = cn + ni*16 + lr;
            if (MODE == 0){
                const float* bp = (o < 256) ? e0 : ((o < 512) ? e1 : e2);
                float bias = bp[o & 255];
                #pragma unroll
                for (int r = 0; r < 4; r++)
                    Y[(size_t)(pbase + r)*ldy + o] = f2bf(acc[mi][ni][r] + bias);
            } else if (MODE == 1){
                float sc = e0[o] * 0.9999950000374997f;   // rsqrt(1+1e-5)*bn_g
                float sh = e1[o];
                #pragma unroll
                for (int r = 0; r < 4; r++){
                    float vv = fmaf(acc[mi][ni][r], sc, sh);
                    Y[(size_t)(pbase + r)*ldy + o] = f2bf(fmaxf(vv, 0.f));
                }
            } else {
                float bias = e0[o];
                const int b = pbase >> 12, nn = pbase & 4095;
                const size_t adr = ((size_t)b*C_ + o)*N_ + nn;
                f32x4 rv = *(const f32x4*)(resid + adr);
                f32x4 ov;
                #pragma unroll
                for (int r = 0; r < 4; r++) ov[r] = acc[mi][ni][r] + bias + rv[r];
                *(f32x4*)(out + adr) = ov;
            }
        }
    }
}

// ---------------- dual-path neighbor attention: 2 waves per point (head halves) ----
__global__ __launch_bounds__(256) void k_attn(
    const unsigned short* __restrict__ QQ, const unsigned short* __restrict__ KVD,
    const int* __restrict__ KNN,
    const float* __restrict__ lnsw, const float* __restrict__ lnsb,
    const float* __restrict__ lndw, const float* __restrict__ lndb,
    unsigned short* __restrict__ F)
{
    __shared__ float q_l[2][2][2][128];     // [ps][wh][sim/dis][dim]
    __shared__ float w_l[2][2][2][4][32];   // [ps][wh][path][h_local][k]
    __shared__ int   idx_l[2][32];
    __shared__ float part_l[2][2][4];

    const int tid = threadIdx.x;
    const int wid = tid >> 6, lane = tid & 63;
    const int ps = wid >> 1, wh = wid & 1;
    const int bid = blockIdx.x;                    // 4096 blocks
    const int pair = ((bid & 1) << 11) | (bid >> 1);   // even bid -> batch 0 XCDs
    const int p = pair*2 + ps;
    const int b = p >> 12;

    {
        const unsigned short* qrow = QQ + (size_t)p*512 + wh*128 + lane*2;
        unsigned int us = *(const unsigned int*)qrow;
        unsigned int ud = *(const unsigned int*)(qrow + 256);
        q_l[ps][wh][0][lane*2]   = bf2f((unsigned short)(us & 0xffff));
        q_l[ps][wh][0][lane*2+1] = bf2f((unsigned short)(us >> 16));
        q_l[ps][wh][1][lane*2]   = bf2f((unsigned short)(ud & 0xffff));
        q_l[ps][wh][1][lane*2+1] = bf2f((unsigned short)(ud >> 16));
        if (wh == 0 && lane < 32) idx_l[ps][lane] = KNN[(size_t)p*K_ + lane];
    }
    __syncthreads();

    const int hh = lane >> 5, kk = lane & 31;
    {
        const int nbr = idx_l[ps][kk];
        const unsigned short* rowb = KVD + (size_t)((b<<12) + nbr)*768;
        bf16x8 kx[2][4], dx[2][4];
        #pragma unroll
        for (int j = 0; j < 2; j++){
            const int h = wh*4 + j*2 + hh;
            const bf16x8* kr = (const bf16x8*)(rowb + h*32);
            const bf16x8* dr = (const bf16x8*)(rowb + 512 + h*32);
            #pragma unroll
            for (int c = 0; c < 4; c++){ kx[j][c] = kr[c]; dx[j][c] = dr[c]; }
        }
        #pragma unroll
        for (int j = 0; j < 2; j++){
            const int hl = j*2 + hh;
            const float* qs = &q_l[ps][wh][0][hl*32];
            const float* qd = &q_l[ps][wh][1][hl*32];
            float s = 0.f, dd = 0.f;
            #pragma unroll
            for (int c = 0; c < 4; c++){
                #pragma unroll
                for (int e = 0; e < 8; e++){
                    const int d = c*8 + e;
                    s = fmaf(qs[d], bf2f((unsigned short)kx[j][c][e]), s);
                    float df = qd[d] - bf2f((unsigned short)dx[j][c][e]);
                    dd = fmaf(df, df, dd);
                }
            }
            float sim = s * 0.17677669529663687f;   // 1/sqrt(32)
            float dist = sqrtf(dd);
            float m1 = sim, m2 = dist;
            #pragma unroll
            for (int off = 1; off < 32; off <<= 1){
                m1 = fmaxf(m1, __shfl_xor(m1, off, 64));
                m2 = fmaxf(m2, __shfl_xor(m2, off, 64));
            }
            float e1v = __expf(sim - m1);
            float e2v = __expf(dist - m2);
            float s1 = e1v, s2 = e2v;
            #pragma unroll
            for (int off = 1; off < 32; off <<= 1){
                s1 += __shfl_xor(s1, off, 64);
                s2 += __shfl_xor(s2, off, 64);
            }
            w_l[ps][wh][0][hl][kk] = e1v / s1;
            w_l[ps][wh][1][hl][kk] = e2v / s2;
        }
    }

    const int tq = lane >> 4, c = lane & 15;
    float cs[8] = {0,0,0,0,0,0,0,0}, cd[8] = {0,0,0,0,0,0,0,0};
    {
        const unsigned short* vbase = KVD + 256 + wh*128 + c*8;
        const int hl = c >> 2;
        int t = tq;
        int nbr = idx_l[ps][t];
        bf16x8 cur = *(const bf16x8*)(vbase + (size_t)((b<<12) + nbr)*768);
        #pragma unroll
        for (int i = 0; i < 8; i++){
            bf16x8 nxt;
            if (i < 7){
                int nn = idx_l[ps][t + 4];
                nxt = *(const bf16x8*)(vbase + (size_t)((b<<12) + nn)*768);
            }
            const float wsv = w_l[ps][wh][0][hl][t];
            const float wdv = w_l[ps][wh][1][hl][t];
            #pragma unroll
            for (int e = 0; e < 8; e++){
                float vf = bf2f((unsigned short)cur[e]);
                cs[e] = fmaf(wsv, vf, cs[e]);
                cd[e] = fmaf(wdv, vf, cd[e]);
            }
            cur = nxt; t += 4;
        }
    }
    #pragma unroll
    for (int e = 0; e < 8; e++){
        cs[e] += __shfl_xor(cs[e], 16, 64); cs[e] += __shfl_xor(cs[e], 32, 64);
        cd[e] += __shfl_xor(cd[e], 16, 64); cd[e] += __shfl_xor(cd[e], 32, 64);
    }
    float s1 = 0.f, q1 = 0.f, s2 = 0.f, q2 = 0.f;
    #pragma unroll
    for (int e = 0; e < 8; e++){
        s1 += cs[e]; q1 = fmaf(cs[e], cs[e], q1);
        s2 += cd[e]; q2 = fmaf(cd[e], cd[e], q2);
    }
    #pragma unroll
    for (int off = 1; off < 16; off <<= 1){
        s1 += __shfl_xor(s1, off, 64); q1 += __shfl_xor(q1, off, 64);
        s2 += __shfl_xor(s2, off, 64); q2 += __shfl_xor(q2, off, 64);
    }
    if (lane == 0){
        part_l[ps][wh][0] = s1; part_l[ps][wh][1] = q1;
        part_l[ps][wh][2] = s2; part_l[ps][wh][3] = q2;
    }
    __syncthreads();
    const float S1 = s1 + part_l[ps][wh^1][0];
    const float Q1 = q1 + part_l[ps][wh^1][1];
    const float S2 = s2 + part_l[ps][wh^1][2];
    const float Q2 = q2 + part_l[ps][wh^1][3];
    const float m1 = S1*(1.f/256.f), m2 = S2*(1.f/256.f);
    const float r1 = rsqrtf(Q1*(1.f/256.f) - m1*m1 + 1e-5f);
    const float r2 = rsqrtf(Q2*(1.f/256.f) - m2*m2 + 1e-5f);

    if (tq == 0){
        bf16x8 ob;
        #pragma unroll
        for (int e = 0; e < 8; e++){
            const int cg = wh*128 + c*8 + e;
            ob[e] = (short)f2bf((cs[e]-m1)*r1*lnsw[cg] + lnsb[cg]);
        }
        *(bf16x8*)(F + (size_t)p*768 + 256 + wh*128 + c*8) = ob;
    } else if (tq == 1){
        bf16x8 ob;
        #pragma unroll
        for (int e = 0; e < 8; e++){
            const int cg = wh*128 + c*8 + e;
            ob[e] = (short)f2bf((cd[e]-m2)*r2*lndw[cg] + lndb[cg]);
        }
        *(bf16x8*)(F + (size_t)p*768 + 512 + wh*128 + c*8) = ob;
    }
}

extern "C" void kernel_launch(void* const* d_in, const int* in_sizes, int n_in,
                              void* d_out, int out_size, void* d_ws, size_t ws_size,
                              hipStream_t stream)
{
    const float* xyzA   = (const float*)d_in[0];
    const float* xyzB   = (const float*)d_in[1];
    const float* featA  = (const float*)d_in[2];
    const float* featB  = (const float*)d_in[3];
    const float* ln_in_w= (const float*)d_in[4];
    const float* ln_in_b= (const float*)d_in[5];
    const float* wq  = (const float*)d_in[6];
    const float* bq  = (const float*)d_in[7];
    const float* wk  = (const float*)d_in[8];
    const float* bk  = (const float*)d_in[9];
    const float* wv  = (const float*)d_in[10];
    const float* bv  = (const float*)d_in[11];
    const float* wqd = (const float*)d_in[12];
    const float* bqd = (const float*)d_in[13];
    const float* wkd = (const float*)d_in[14];
    const float* bkd = (const float*)d_in[15];
    const float* lnsw = (const float*)d_in[16];
    const float* lnsb = (const float*)d_in[17];
    const float* lndw = (const float*)d_in[18];
    const float* lndb = (const float*)d_in[19];
    const float* fw1 = (const float*)d_in[20];
    const float* bng = (const float*)d_in[21];
    const float* bnb = (const float*)d_in[22];
    const float* fw2 = (const float*)d_in[23];
    const float* fb2 = (const float*)d_in[24];
    float* out = (float*)d_out;
    char* ws = (char*)d_ws;

    unsigned short* F    = (unsigned short*)(ws + 0);          // 8192*768 bf16
    unsigned short* XBT  = (unsigned short*)(ws + 12582912);   // 8192*256
    unsigned short* QQ   = (unsigned short*)(ws + 16777216);   // 8192*512
    unsigned short* KVD  = (unsigned short*)(ws + 25165824);   // 8192*768
    unsigned short* Y1   = (unsigned short*)(ws + 37748736);   // 8192*512 (GEMM) ; PB (knn, earlier)
    f32x4*          PB   = (f32x4*)(ws + 37748736);            // 8192*16B, dead before fus1
    int*            KNNi = (int*)(ws + 46137344);              // 8192*32
    float*          STATS= (float*)(ws + 47185920);            // 8192*2
    unsigned short* Wb   = (unsigned short*)(ws + 47251456);   // 851968 bf16
    unsigned short* WQcat = Wb;                // 512x256
    unsigned short* WKVD  = Wb + 131072;       // 768x256
    unsigned short* W1b   = Wb + 327680;       // 512x768
    unsigned short* W2b   = Wb + 720896;       // 256x512

    k_cvt_all<<<3328, 256, 0, stream>>>(wq, wqd, wk, wv, wkd, fw1, fw2, Wb);
    k_prep<<<32, 256, 0, stream>>>(xyzB, PB);

    k_ln_stats<<<128, 256, 0, stream>>>(featA, STATS);
    k_transpose<1><<<dim3(64,4,2), 256, 0, stream>>>(featA, F, 768, STATS, ln_in_w, ln_in_b);
    k_transpose<0><<<dim3(64,4,2), 256, 0, stream>>>(featB, XBT, 256, nullptr, nullptr, nullptr);
    k_knn<<<2048, 256, 0, stream>>>(xyzA, PB, KNNi);

    k_gemm<0><<<dim3(64,8), 256, 0, stream>>>(F,   768, WQcat, 256, bq, bqd, nullptr, QQ, 512, nullptr, nullptr);
    k_gemm<0><<<dim3(64,12), 256, 0, stream>>>(XBT, 256, WKVD, 256, bk, bv, bkd, KVD, 768, nullptr, nullptr);

    k_attn<<<4096, 256, 0, stream>>>(QQ, KVD, KNNi, lnsw, lnsb, lndw, lndb, F);

    k_gemm<1><<<dim3(64,8), 256, 0, stream>>>(F,  768, W1b, 768, bng, bnb, nullptr, Y1, 512, nullptr, nullptr);
    k_gemm<2><<<dim3(64,4), 256, 0, stream>>>(Y1, 512, W2b, 512, fb2, nullptr, nullptr, nullptr, 0, featA, out);
}